// Round 5
// baseline (377.794 us; speedup 1.0000x reference)
//
#include <hip/hip_runtime.h>
#include <hip/hip_bf16.h>
#include <cmath>

// Problem constants
#define B_    4
#define T_    1000000
#define E_    8
#define C_    128
#define NCH   512        // fused conv output channels (both branches, 2*256)
#define KK    4096       // GEMM K = E * kernel (8*512); windows are contiguous rows
#define NKS   4          // split-K ways
#define KH    1024       // split-K slice length
#define TOUT  1953       // (1e6 - 512)/512 + 1
#define TP    1956       // padded t stride (mult of 4) for aligned float4 stores
#define NT2   31         // ceil(1953/64) tiles of 64 along t
#define KSOFF ((size_t)NCH * B_ * TP)   // u2 k-slice stride (elements)

typedef __attribute__((ext_vector_type(8))) short bf16x8;   // 8 bf16 = 4 VGPRs
typedef __attribute__((ext_vector_type(4))) float f32x4;

__device__ __forceinline__ float sigmoidf_(float v) { return 1.f / (1.f + __expf(-v)); }

__device__ __forceinline__ void gl2lds16(const void* g, void* l) {
  __builtin_amdgcn_global_load_lds((const __attribute__((address_space(1))) void*)g,
                                   (__attribute__((address_space(3))) void*)l, 16, 0, 0);
}

// ---------------------------------------------------------------------------
// Kernel B: weights (o,e,kpos) -> bf16 Wtb[n][kpos*8+e], n = br*256 + o.
// LDS transpose so both global read and write are coalesced. bias_t fp32.
__global__ __launch_bounds__(256) void prep_w(
    const float* __restrict__ wc, const float* __restrict__ bc,
    const float* __restrict__ wm, const float* __restrict__ bm,
    __hip_bfloat16* __restrict__ Wtb, float* __restrict__ bias_t) {
  __shared__ float row[KK];
  int n = blockIdx.x;                 // 0..511
  int br = n >> 8, o = n & 255;
  const float* wsrc = (br ? wm : wc) + (size_t)o * KK;
  for (int i = threadIdx.x; i < KK; i += 256) row[i] = wsrc[i];   // [e][kpos]
  __syncthreads();
  for (int i = threadIdx.x; i < KK; i += 256) {
    int kpos = i >> 3, e = i & 7;
    Wtb[(size_t)n * KK + i] = __float2bfloat16(row[e * 512 + kpos]);
  }
  if (threadIdx.x == 0) bias_t[n] = (br ? bm : bc)[o];
}

// ---------------------------------------------------------------------------
// Kernel C: bf16 MFMA GEMM, fused fp32->bf16 A-conversion, split-K=4 for TLP
// (grid 2048 = up to 4 blocks/CU; barrier-paced latency of one block hides
// behind the other three). Double-buffered LDS, B DMA issued AFTER the
// barrier. XCD swizzle: the 4 n-blocks of a (t,b,ks) group share L%8 = XCD so
// the fp32 A-slices are HBM-fetched once per group (verified R4: FETCH 254->82MB).
// u2 layout: [ks][n][b][TP]; bias applied downstream.
__global__ __launch_bounds__(256, 4) void mfma_gemm(
    const float* __restrict__ x, const __hip_bfloat16* __restrict__ Wtb,
    float* __restrict__ u2) {
  __shared__ __hip_bfloat16 As[2][128 * 32];
  __shared__ __hip_bfloat16 Bs[2][128 * 32];
  const int tid  = threadIdx.x;
  const int lane = tid & 63, wave = tid >> 6;
  const int wm = wave >> 1, wn = wave & 1;

  // Swizzle decode: L = xcd + 8*nb + 32*g; group (g,xcd) spans nb=0..3.
  const int L   = blockIdx.x;
  const int xcd = L & 7;
  const int r   = L >> 3;
  const int nb  = r & 3;
  const int g   = r >> 2;                 // 0..63
  const int tb  = g * 8 + xcd;            // 0..511
  const int n0  = nb * 128;
  const int t0  = (tb & 15) * 128;
  const int bz  = tb >> 4;                // 0..31
  const int b   = bz & 3, ks = bz >> 2;   // 4 batches x 4 k-slices
  const size_t kbase = (size_t)ks * KH;

  // B staging (DMA): chunk l = it*256 + tid of 16B; row = l>>2, col8 = (l&3)*8.
  const int r0 = tid >> 2;            // 0..63
  const int q8 = (tid & 3) * 8;
  const __hip_bfloat16* bS = Wtb + (size_t)(n0 + r0) * KK + kbase + q8;

  // A staging (regs): chunk c0 = tid (row tid>>2, col (tid&3)*8), c1 = 256+tid.
  const int ar = tid >> 2;
  const int ac = (tid & 3) * 8;
  int row0 = t0 + ar;      if (row0 > TOUT - 1) row0 = TOUT - 1;   // clamp: garbage
  int row1 = t0 + 64 + ar; if (row1 > TOUT - 1) row1 = TOUT - 1;   // rows discarded
  const float* aP0 = x + (size_t)b * 8000000ull + (size_t)row0 * KK + kbase + ac;
  const float* aP1 = x + (size_t)b * 8000000ull + (size_t)row1 * KK + kbase + ac;

  f32x4 acc[4][4];
#pragma unroll
  for (int i = 0; i < 4; ++i)
#pragma unroll
    for (int j = 0; j < 4; ++j) acc[i][j] = (f32x4)(0.0f);

  const int mrow = lane & 15;
  const int kq   = (lane >> 4) * 8;

  float4 a0, a1, a2, a3;
  // Prologue: stage step 0 into buf 0.
  a0 = *(const float4*)(aP0);     a1 = *(const float4*)(aP0 + 4);
  a2 = *(const float4*)(aP1);     a3 = *(const float4*)(aP1 + 4);
  gl2lds16(bS,           &Bs[0][wave * 512]);
  gl2lds16(bS + 64 * KK, &Bs[0][2048 + wave * 512]);
  {
    union { __hip_bfloat16 h[8]; bf16x8 v; } u0, u1;
    u0.h[0]=__float2bfloat16(a0.x); u0.h[1]=__float2bfloat16(a0.y);
    u0.h[2]=__float2bfloat16(a0.z); u0.h[3]=__float2bfloat16(a0.w);
    u0.h[4]=__float2bfloat16(a1.x); u0.h[5]=__float2bfloat16(a1.y);
    u0.h[6]=__float2bfloat16(a1.z); u0.h[7]=__float2bfloat16(a1.w);
    u1.h[0]=__float2bfloat16(a2.x); u1.h[1]=__float2bfloat16(a2.y);
    u1.h[2]=__float2bfloat16(a2.z); u1.h[3]=__float2bfloat16(a2.w);
    u1.h[4]=__float2bfloat16(a3.x); u1.h[5]=__float2bfloat16(a3.y);
    u1.h[6]=__float2bfloat16(a3.z); u1.h[7]=__float2bfloat16(a3.w);
    *(bf16x8*)&As[0][tid * 8]        = u0.v;
    *(bf16x8*)&As[0][2048 + tid * 8] = u1.v;
  }

  for (int s = 0; s < KH / 32; ++s) {   // 32 steps
    const int cur = s & 1, nxt = cur ^ 1;
    __syncthreads();   // drains DMA for buf[cur] (in flight during prev MFMA) + lds writes
    if (s < KH / 32 - 1) {
      // Issue next B DMA now: it has the whole MFMA phase before next barrier.
      gl2lds16(bS + (s + 1) * 32,           &Bs[nxt][wave * 512]);
      gl2lds16(bS + (s + 1) * 32 + 64 * KK, &Bs[nxt][2048 + wave * 512]);
      // Next A global loads (complete during MFMA phase).
      a0 = *(const float4*)(aP0 + (s + 1) * 32);
      a1 = *(const float4*)(aP0 + (s + 1) * 32 + 4);
      a2 = *(const float4*)(aP1 + (s + 1) * 32);
      a3 = *(const float4*)(aP1 + (s + 1) * 32 + 4);
    }

    bf16x8 af[4], bf[4];
#pragma unroll
    for (int i = 0; i < 4; ++i)
      af[i] = *(const bf16x8*)&As[cur][(wm * 64 + i * 16 + mrow) * 32 + kq];
#pragma unroll
    for (int j = 0; j < 4; ++j)
      bf[j] = *(const bf16x8*)&Bs[cur][(wn * 64 + j * 16 + mrow) * 32 + kq];
#pragma unroll
    for (int i = 0; i < 4; ++i)
#pragma unroll
      for (int j = 0; j < 4; ++j)
        acc[i][j] = __builtin_amdgcn_mfma_f32_16x16x32_bf16(af[i], bf[j], acc[i][j], 0, 0, 0);

    if (s < KH / 32 - 1) {
      union { __hip_bfloat16 h[8]; bf16x8 v; } u0, u1;
      u0.h[0]=__float2bfloat16(a0.x); u0.h[1]=__float2bfloat16(a0.y);
      u0.h[2]=__float2bfloat16(a0.z); u0.h[3]=__float2bfloat16(a0.w);
      u0.h[4]=__float2bfloat16(a1.x); u0.h[5]=__float2bfloat16(a1.y);
      u0.h[6]=__float2bfloat16(a1.z); u0.h[7]=__float2bfloat16(a1.w);
      u1.h[0]=__float2bfloat16(a2.x); u1.h[1]=__float2bfloat16(a2.y);
      u1.h[2]=__float2bfloat16(a2.z); u1.h[3]=__float2bfloat16(a2.w);
      u1.h[4]=__float2bfloat16(a3.x); u1.h[5]=__float2bfloat16(a3.y);
      u1.h[6]=__float2bfloat16(a3.z); u1.h[7]=__float2bfloat16(a3.w);
      *(bf16x8*)&As[nxt][tid * 8]        = u0.v;
      *(bf16x8*)&As[nxt][2048 + tid * 8] = u1.v;
    }
  }

  // Epilogue. C/D layout: col = lane&15, row = (lane>>4)*4 + reg.
  const int crow = (lane >> 4) * 4;
  const int ccol = lane & 15;
#pragma unroll
  for (int j = 0; j < 4; ++j) {
    int n = n0 + wn * 64 + j * 16 + ccol;
    float* urow = u2 + ((size_t)(ks * NCH + n) * B_ + b) * TP;
#pragma unroll
    for (int i = 0; i < 4; ++i) {
      int bt = t0 + wm * 64 + i * 16 + crow;   // mult of 4
      if (bt < TOUT) *(f32x4*)(urow + bt) = acc[i][j];  // may touch pad [1953,1956)
    }
  }
}

// ---------------------------------------------------------------------------
// Kernel 2: sum k-slices + bias + GLU (on load from u2) -> 1x1 share conv +
// leaky. br==1: store h_main; br==0: per-tile max over t -> gct_part.
__global__ __launch_bounds__(256) void share_act(
    const float* __restrict__ u2, const float* __restrict__ bias_t,
    const float* __restrict__ wsc, const float* __restrict__ bsc,
    const float* __restrict__ wsm, const float* __restrict__ bsm,
    float* __restrict__ hmain, float* __restrict__ gct_part) {
  __shared__ float Wl[128 * 132];   // Wl[cp*132 + cout] = ws[cout, cp]
  __shared__ float ul[128 * 68];    // ul[cp*68 + t]
  const int tid  = threadIdx.x;
  const int tile = blockIdx.x;      // 0..30
  const int b    = blockIdx.y;
  const int br   = blockIdx.z;
  const int t0   = tile * 64;
  const float* ws = br ? wsm : wsc;
  const float* bs = br ? bsm : bsc;

  for (int g = tid; g < 16384; g += 256) {
    int co = g >> 7, cp = g & 127;
    Wl[cp * 132 + co] = ws[g];
  }
  const size_t base_v = ((size_t)(br * 256) * B_ + b) * TP;
  const size_t base_g = ((size_t)(br * 256 + 128) * B_ + b) * TP;
  for (int g = tid; g < 8192; g += 256) {
    int cp = g >> 6, t = g & 63;
    float v = 0.f;
    if (t0 + t < TOUT) {
      size_t ov = base_v + (size_t)cp * B_ * TP + t0 + t;
      size_t og = base_g + (size_t)cp * B_ * TP + t0 + t;
      float va = u2[ov] + u2[KSOFF + ov] + u2[2*KSOFF + ov] + u2[3*KSOFF + ov]
               + bias_t[br * 256 + cp];
      float vg = u2[og] + u2[KSOFF + og] + u2[2*KSOFF + og] + u2[3*KSOFF + og]
               + bias_t[br * 256 + 128 + cp];
      v = va * sigmoidf_(vg);
    }
    ul[cp * 68 + t] = v;
  }
  __syncthreads();

  const int ty = tid >> 4, tx = tid & 15;  // c-groups x t-groups
  float acc[8][4];
#pragma unroll
  for (int i = 0; i < 8; ++i)
#pragma unroll
    for (int j = 0; j < 4; ++j) acc[i][j] = 0.f;

  for (int cp = 0; cp < 128; ++cp) {
    float4 a0 = *(const float4*)&Wl[cp*132 + ty*4];
    float4 a1 = *(const float4*)&Wl[cp*132 + 64 + ty*4];
    float4 b4 = *(const float4*)&ul[cp*68 + tx*4];
    float av[8] = {a0.x,a0.y,a0.z,a0.w,a1.x,a1.y,a1.z,a1.w};
    float bv[4] = {b4.x,b4.y,b4.z,b4.w};
#pragma unroll
    for (int i = 0; i < 8; ++i)
#pragma unroll
      for (int j = 0; j < 4; ++j) acc[i][j] = fmaf(av[i], bv[j], acc[i][j]);
  }

  float mloc[8];
#pragma unroll
  for (int i = 0; i < 8; ++i) mloc[i] = -INFINITY;
#pragma unroll
  for (int i = 0; i < 8; ++i) {
    int c = (i < 4) ? (ty*4 + i) : (64 + ty*4 + (i - 4));
    float bias = bs[c];
#pragma unroll
    for (int j = 0; j < 4; ++j) {
      int t = t0 + tx*4 + j;
      if (t >= TOUT) continue;
      float v = acc[i][j] + bias;
      v = (v >= 0.f) ? v : 0.01f * v;
      if (br == 1) {
        hmain[((size_t)b * 128 + c) * TOUT + t] = v;
      } else {
        mloc[i] = fmaxf(mloc[i], v);
      }
    }
  }
  if (br == 0) {
    __syncthreads();               // done reading ul; reuse as reduction buffer
    float* red = ul;               // 128*16 region
#pragma unroll
    for (int i = 0; i < 8; ++i) {
      int c = (i < 4) ? (ty*4 + i) : (64 + ty*4 + (i - 4));
      red[c * 16 + tx] = mloc[i];
    }
    __syncthreads();
    if (tid < 128) {
      float m = -INFINITY;
#pragma unroll
      for (int k = 0; k < 16; ++k) m = fmaxf(m, red[tid * 16 + k]);
      gct_part[((size_t)b * 128 + tid) * NT2 + tile] = m;
    }
  }
}

// ---------------------------------------------------------------------------
// Kernel 3: gct = max over tiles; q = tanh(gct @ Wp^T + bp). One block per b.
__global__ void gct_q(const float* __restrict__ gct_part, const float* __restrict__ wp,
                      const float* __restrict__ bp, float* __restrict__ q) {
  int b = blockIdx.x, tid = threadIdx.x;   // 128 threads
  __shared__ float g[128];
  float m = -INFINITY;
  for (int tl = 0; tl < NT2; ++tl) m = fmaxf(m, gct_part[((size_t)b * 128 + tid) * NT2 + tl]);
  g[tid] = m;
  __syncthreads();
  float s = bp[tid];
  for (int c = 0; c < 128; ++c) s = fmaf(g[c], wp[tid * 128 + c], s);
  q[b * 128 + tid] = tanhf(s);
}

// ---------------------------------------------------------------------------
// Kernel 4: gate[t] = sigmoid(sum_c h*q); out_part = per-tile max_t h*gate.
__global__ __launch_bounds__(256) void gate_max(
    const float* __restrict__ hmain, const float* __restrict__ q,
    float* __restrict__ out_part) {
  __shared__ float hl[128 * 68];
  __shared__ float ql[128];
  __shared__ float red[256];
  __shared__ float gl[64];
  int tid = threadIdx.x, tile = blockIdx.x, b = blockIdx.y;
  int t0 = tile * 64;
  for (int g = tid; g < 8192; g += 256) {
    int c = g >> 6, t = g & 63;
    hl[c * 68 + t] = (t0 + t < TOUT) ? hmain[((size_t)b * 128 + c) * TOUT + t0 + t] : 0.f;
  }
  if (tid < 128) ql[tid] = q[b * 128 + tid];
  __syncthreads();
  {
    int t = tid & 63, cy = tid >> 6;
    float s = 0.f;
#pragma unroll
    for (int cc = 0; cc < 32; ++cc) s = fmaf(hl[(cy * 32 + cc) * 68 + t], ql[cy * 32 + cc], s);
    red[cy * 64 + t] = s;
  }
  __syncthreads();
  if (tid < 64) {
    float s = red[tid] + red[64 + tid] + red[128 + tid] + red[192 + tid];
    gl[tid] = sigmoidf_(s);
  }
  __syncthreads();
  {
    int c = tid >> 1, th = tid & 1;
    float m = -INFINITY;
#pragma unroll
    for (int tt = 0; tt < 32; ++tt) {
      int t = th * 32 + tt;
      if (t0 + t < TOUT) m = fmaxf(m, hl[c * 68 + t] * gl[t]);
    }
    red[c * 2 + th] = m;
  }
  __syncthreads();
  if (tid < 128) out_part[((size_t)b * 128 + tid) * NT2 + tile] = fmaxf(red[tid * 2], red[tid * 2 + 1]);
}

// ---------------------------------------------------------------------------
// Kernel 5: final max over tiles -> d_out (B,C) row-major.
__global__ void final_max(const float* __restrict__ out_part, float* __restrict__ out) {
  int idx = blockIdx.x * 256 + threadIdx.x;
  if (idx < 512) {
    float m = -INFINITY;
    for (int tl = 0; tl < NT2; ++tl) m = fmaxf(m, out_part[(size_t)idx * NT2 + tl]);
    out[idx] = m;
  }
}

// ---------------------------------------------------------------------------
extern "C" void kernel_launch(void* const* d_in, const int* in_sizes, int n_in,
                              void* d_out, int out_size, void* d_ws, size_t ws_size,
                              hipStream_t stream) {
  const float* x      = (const float*)d_in[0];
  const float* ctx_w  = (const float*)d_in[1];
  const float* ctx_b  = (const float*)d_in[2];
  const float* ctx_sw = (const float*)d_in[3];
  const float* ctx_sb = (const float*)d_in[4];
  const float* main_w = (const float*)d_in[5];
  const float* main_b = (const float*)d_in[6];
  const float* main_sw= (const float*)d_in[7];
  const float* main_sb= (const float*)d_in[8];
  const float* gp_w   = (const float*)d_in[9];
  const float* gp_b   = (const float*)d_in[10];

  char* w = (char*)d_ws;
  __hip_bfloat16* Wtb = (__hip_bfloat16*)(w);              // 512*4096*2 = 4,194,304
  float* bias_t  = (float*)(w + 4194304);                  // 512*4 = 2048
  float* u2      = (float*)(w + 4196352);                  // 4*512*4*TP*4 = 64,094,208
  float* hmain   = (float*)(w + 68290560);                 // 4*128*1953*4 = 3,999,744
  float* gct_part= (float*)(w + 72290304);                 // 4*128*31*4 = 63,488
  float* q       = (float*)(w + 72353792);                 // 512*4
  float* out_part= (float*)(w + 72355840);                 // 63,488
  // total 72,419,328 bytes — R1 used 91.4MB successfully, so ws_size suffices.

  prep_w<<<NCH, 256, 0, stream>>>(ctx_w, ctx_b, main_w, main_b, Wtb, bias_t);
  mfma_gemm<<<2048, 256, 0, stream>>>(x, Wtb, u2);
  share_act<<<dim3(NT2, B_, 2), 256, 0, stream>>>(u2, bias_t, ctx_sw, ctx_sb,
                                                  main_sw, main_sb, hmain, gct_part);
  gct_q<<<B_, 128, 0, stream>>>(gct_part, gp_w, gp_b, q);
  gate_max<<<dim3(NT2, B_), 256, 0, stream>>>(hmain, q, out_part);
  final_max<<<2, 256, 0, stream>>>(out_part, (float*)d_out);
}

// Round 6
// 315.849 us; speedup vs baseline: 1.1961x; 1.1961x over previous
//
#include <hip/hip_runtime.h>
#include <hip/hip_bf16.h>
#include <cmath>

// Problem constants
#define B_    4
#define T_    1000000
#define E_    8
#define C_    128
#define NCH   512        // fused conv output channels (both branches, 2*256)
#define KK    4096       // GEMM K = E * kernel (8*512); windows are contiguous rows
#define TOUT  1953       // (1e6 - 512)/512 + 1
#define TP    1956       // padded t stride (mult of 4) for aligned float4 stores
#define TPAD  2048       // padded t rows per batch in xb2 (zero-filled past 1952)
#define NT2   31         // ceil(1953/64) tiles of 64 along t

typedef __attribute__((ext_vector_type(8))) short bf16x8;   // 8 bf16 = 4 VGPRs
typedef __attribute__((ext_vector_type(4))) float f32x4;

__device__ __forceinline__ float sigmoidf_(float v) { return 1.f / (1.f + __expf(-v)); }

// ---------------------------------------------------------------------------
// Fragment-ordered operand layout ("frag chunk" = 16 rows x 32 k, stored as
// [lane][8] in exact MFMA A/B operand order: lane = (k>>3 & 3)*16 + (row&15),
// j = k&7). One chunk = 512 elems = 1KB bf16; a fragment load is then ONE
// fully-coalesced global_load_dwordx4 per lane (lane*16B).
// xb2: [b][tt=t/16][kc=k/32][lane][8]   (b*2^23 elements per batch)
// Wn2: [nt=n/16][kc][lane][8]
//
// Kernel A: merged input prep, one launch.
//  - blocks [0,512): weight prep for channel n (LDS transpose of (e,kpos)->k)
//  - blocks [512, 512+16384): x fp32 -> bf16 frag-ordered, zero pad t>=TOUT
__global__ __launch_bounds__(256) void prep_inputs(
    const float* __restrict__ x,
    const float* __restrict__ wc, const float* __restrict__ bc,
    const float* __restrict__ wm, const float* __restrict__ bm,
    __hip_bfloat16* __restrict__ xb2, __hip_bfloat16* __restrict__ Wn2,
    float* __restrict__ bias_t) {
  __shared__ float row[KK];
  const int bid = blockIdx.x;
  if (bid < NCH) {
    const int n = bid, br = n >> 8, o = n & 255;
    const float* wsrc = (br ? wm : wc) + (size_t)o * KK;
    for (int i = threadIdx.x; i < KK; i += 256) row[i] = wsrc[i];   // [e][kpos]
    __syncthreads();
    const int nt = n >> 4, nr = n & 15;
    for (int k = threadIdx.x; k < KK; k += 256) {
      int kpos = k >> 3, e = k & 7;                 // W[n][k] with k = kpos*8+e
      size_t addr = (((size_t)nt * 128 + (k >> 5)) * 64
                     + (size_t)((k >> 3) & 3) * 16 + nr) * 8 + (k & 7);
      Wn2[addr] = __float2bfloat16(row[e * 512 + kpos]);
    }
    if (threadIdx.x == 0) bias_t[n] = (br ? bm : bc)[o];
  } else {
    size_t gid = (size_t)(bid - NCH) * 256 + threadIdx.x;
    size_t idx8 = gid * 8;                       // element index in [4][2^23]
    size_t b = idx8 >> 23, rem = idx8 & ((1ull << 23) - 1);
    int lane = (int)((rem >> 3) & 63);
    int kc   = (int)((rem >> 9) & 127);
    int tt   = (int)(rem >> 16);
    int t = tt * 16 + (lane & 15);
    int k = kc * 32 + (lane >> 4) * 8;
    union { __hip_bfloat16 h[8]; uint4 u; } o;
    if (t < TOUT) {
      const float* src = x + b * 8000000ull + (size_t)t * KK + k;
      float4 f0 = *(const float4*)(src);
      float4 f1 = *(const float4*)(src + 4);
      o.h[0] = __float2bfloat16(f0.x); o.h[1] = __float2bfloat16(f0.y);
      o.h[2] = __float2bfloat16(f0.z); o.h[3] = __float2bfloat16(f0.w);
      o.h[4] = __float2bfloat16(f1.x); o.h[5] = __float2bfloat16(f1.y);
      o.h[6] = __float2bfloat16(f1.z); o.h[7] = __float2bfloat16(f1.w);
    } else {
      o.u = make_uint4(0, 0, 0, 0);
    }
    *(uint4*)(xb2 + idx8) = o.u;
  }
}

// ---------------------------------------------------------------------------
// Kernel C: barrier-free, LDS-free register GEMM. C[t,n] = sum_k A[t,k]W[n,k].
// Block = 512 thr = 8 waves (4 t-waves x 2 n-waves), block tile 128x128,
// wave tile 32t x 64n (acc 2x4 of 16x16). BK=64 per set; two register sets
// ping-pong so the next set's 12 coalesced loads are in flight during the
// current set's 32 MFMAs. No __syncthreads anywhere in the loop -> no vmcnt(0)
// convoy. Grid 256 = 1 block/CU; XCD swizzle: 4 n-groups of one (t,b) share
// L%8 = XCD so A re-reads hit that XCD's L2 (R4: FETCH 254->82MB proof).
__global__ __launch_bounds__(512, 2) void mfma_gemm(
    const __hip_bfloat16* __restrict__ xb2, const __hip_bfloat16* __restrict__ Wn2,
    float* __restrict__ u2) {
  const int tid  = threadIdx.x;
  const int lane = tid & 63, wave = tid >> 6;
  const int wt = wave & 3, wn = wave >> 2;

  // Swizzle: L = xcd + 8*(nb + 4*sh); s = sh*8 + xcd = (t,b) group 0..63.
  const int L   = blockIdx.x;
  const int xcd = L & 7;
  const int r   = L >> 3;
  const int nb  = r & 3;
  const int sh  = r >> 2;                 // 0..7
  const int s   = sh * 8 + xcd;           // 0..63
  const int tblk = s & 15, b = s >> 4;
  const int t0 = tblk * 128, n0 = nb * 128;

  const size_t FR = 512;                  // elems per frag chunk
  const __hip_bfloat16* aB = xb2
      + ((size_t)(b * 128 + (t0 >> 4) + wt * 2) * 128) * FR + (size_t)lane * 8;
  const __hip_bfloat16* bB = Wn2
      + ((size_t)((n0 >> 4) + wn * 4) * 128) * FR + (size_t)lane * 8;
  // A frag (i,kc) at aB + (i*128+kc)*FR ; B frag (j,kc) at bB + (j*128+kc)*FR

  f32x4 acc[2][4];
#pragma unroll
  for (int i = 0; i < 2; ++i)
#pragma unroll
    for (int j = 0; j < 4; ++j) acc[i][j] = (f32x4)(0.0f);

  bf16x8 A0[2][2], B0[4][2], A1[2][2], B1[4][2];

  auto load_set = [&](bf16x8 (&aF)[2][2], bf16x8 (&bF)[4][2], int kc) {
#pragma unroll
    for (int i = 0; i < 2; ++i)
#pragma unroll
      for (int c = 0; c < 2; ++c)
        aF[i][c] = *(const bf16x8*)(aB + (size_t)(i * 128 + kc + c) * FR);
#pragma unroll
    for (int j = 0; j < 4; ++j)
#pragma unroll
      for (int c = 0; c < 2; ++c)
        bF[j][c] = *(const bf16x8*)(bB + (size_t)(j * 128 + kc + c) * FR);
  };
  auto do_mfma = [&](bf16x8 (&aF)[2][2], bf16x8 (&bF)[4][2]) {
#pragma unroll
    for (int c = 0; c < 2; ++c)
#pragma unroll
      for (int i = 0; i < 2; ++i)
#pragma unroll
        for (int j = 0; j < 4; ++j)
          acc[i][j] = __builtin_amdgcn_mfma_f32_16x16x32_bf16(aF[i][c], bF[j][c],
                                                              acc[i][j], 0, 0, 0);
  };

  load_set(A0, B0, 0);
  for (int kc = 0; kc < 128; kc += 4) {
    load_set(A1, B1, kc + 2);
    do_mfma(A0, B0);
    if (kc + 4 < 128) load_set(A0, B0, kc + 4);
    do_mfma(A1, B1);
  }

  // Epilogue. C/D layout: col = lane&15, row = (lane>>4)*4 + reg.
  const int crow = (lane >> 4) * 4;
  const int ccol = lane & 15;
#pragma unroll
  for (int j = 0; j < 4; ++j) {
    int n = n0 + wn * 64 + j * 16 + ccol;
    float* urow = u2 + ((size_t)n * B_ + b) * TP;
#pragma unroll
    for (int i = 0; i < 2; ++i) {
      int t = t0 + wt * 32 + i * 16 + crow;    // mult of 4
      if (t < TOUT) *(f32x4*)(urow + t) = acc[i][j];  // may touch pad [1953,1956)
    }
  }
}

// ---------------------------------------------------------------------------
// Kernel 2: bias + GLU (on load from u2) -> 1x1 share conv + leaky.
// br==1: store h_main; br==0: per-tile max over t -> gct_part.
__global__ __launch_bounds__(256) void share_act(
    const float* __restrict__ u2, const float* __restrict__ bias_t,
    const float* __restrict__ wsc, const float* __restrict__ bsc,
    const float* __restrict__ wsm, const float* __restrict__ bsm,
    float* __restrict__ hmain, float* __restrict__ gct_part) {
  __shared__ float Wl[128 * 132];   // Wl[cp*132 + cout] = ws[cout, cp]
  __shared__ float ul[128 * 68];    // ul[cp*68 + t]
  const int tid  = threadIdx.x;
  const int tile = blockIdx.x;      // 0..30
  const int b    = blockIdx.y;
  const int br   = blockIdx.z;
  const int t0   = tile * 64;
  const float* ws = br ? wsm : wsc;
  const float* bs = br ? bsm : bsc;

  for (int g = tid; g < 16384; g += 256) {
    int co = g >> 7, cp = g & 127;
    Wl[cp * 132 + co] = ws[g];
  }
  const size_t base_v = ((size_t)(br * 256) * B_ + b) * TP;
  const size_t base_g = ((size_t)(br * 256 + 128) * B_ + b) * TP;
  for (int g = tid; g < 8192; g += 256) {
    int cp = g >> 6, t = g & 63;
    float v = 0.f;
    if (t0 + t < TOUT) {
      float va = u2[base_v + (size_t)cp * B_ * TP + t0 + t] + bias_t[br * 256 + cp];
      float vg = u2[base_g + (size_t)cp * B_ * TP + t0 + t] + bias_t[br * 256 + 128 + cp];
      v = va * sigmoidf_(vg);
    }
    ul[cp * 68 + t] = v;
  }
  __syncthreads();

  const int ty = tid >> 4, tx = tid & 15;  // c-groups x t-groups
  float acc[8][4];
#pragma unroll
  for (int i = 0; i < 8; ++i)
#pragma unroll
    for (int j = 0; j < 4; ++j) acc[i][j] = 0.f;

  for (int cp = 0; cp < 128; ++cp) {
    float4 a0 = *(const float4*)&Wl[cp*132 + ty*4];
    float4 a1 = *(const float4*)&Wl[cp*132 + 64 + ty*4];
    float4 b4 = *(const float4*)&ul[cp*68 + tx*4];
    float av[8] = {a0.x,a0.y,a0.z,a0.w,a1.x,a1.y,a1.z,a1.w};
    float bv[4] = {b4.x,b4.y,b4.z,b4.w};
#pragma unroll
    for (int i = 0; i < 8; ++i)
#pragma unroll
      for (int j = 0; j < 4; ++j) acc[i][j] = fmaf(av[i], bv[j], acc[i][j]);
  }

  float mloc[8];
#pragma unroll
  for (int i = 0; i < 8; ++i) mloc[i] = -INFINITY;
#pragma unroll
  for (int i = 0; i < 8; ++i) {
    int c = (i < 4) ? (ty*4 + i) : (64 + ty*4 + (i - 4));
    float bias = bs[c];
#pragma unroll
    for (int j = 0; j < 4; ++j) {
      int t = t0 + tx*4 + j;
      if (t >= TOUT) continue;
      float v = acc[i][j] + bias;
      v = (v >= 0.f) ? v : 0.01f * v;
      if (br == 1) {
        hmain[((size_t)b * 128 + c) * TOUT + t] = v;
      } else {
        mloc[i] = fmaxf(mloc[i], v);
      }
    }
  }
  if (br == 0) {
    __syncthreads();               // done reading ul; reuse as reduction buffer
    float* red = ul;               // 128*16 region
#pragma unroll
    for (int i = 0; i < 8; ++i) {
      int c = (i < 4) ? (ty*4 + i) : (64 + ty*4 + (i - 4));
      red[c * 16 + tx] = mloc[i];
    }
    __syncthreads();
    if (tid < 128) {
      float m = -INFINITY;
#pragma unroll
      for (int k = 0; k < 16; ++k) m = fmaxf(m, red[tid * 16 + k]);
      gct_part[((size_t)b * 128 + tid) * NT2 + tile] = m;
    }
  }
}

// ---------------------------------------------------------------------------
// Kernel 3: gct = max over tiles; q = tanh(gct @ Wp^T + bp). One block per b.
__global__ void gct_q(const float* __restrict__ gct_part, const float* __restrict__ wp,
                      const float* __restrict__ bp, float* __restrict__ q) {
  int b = blockIdx.x, tid = threadIdx.x;   // 128 threads
  __shared__ float g[128];
  float m = -INFINITY;
  for (int tl = 0; tl < NT2; ++tl) m = fmaxf(m, gct_part[((size_t)b * 128 + tid) * NT2 + tl]);
  g[tid] = m;
  __syncthreads();
  float s = bp[tid];
  for (int c = 0; c < 128; ++c) s = fmaf(g[c], wp[tid * 128 + c], s);
  q[b * 128 + tid] = tanhf(s);
}

// ---------------------------------------------------------------------------
// Kernel 4: gate[t] = sigmoid(sum_c h*q); out_part = per-tile max_t h*gate.
__global__ __launch_bounds__(256) void gate_max(
    const float* __restrict__ hmain, const float* __restrict__ q,
    float* __restrict__ out_part) {
  __shared__ float hl[128 * 68];
  __shared__ float ql[128];
  __shared__ float red[256];
  __shared__ float gl[64];
  int tid = threadIdx.x, tile = blockIdx.x, b = blockIdx.y;
  int t0 = tile * 64;
  for (int g = tid; g < 8192; g += 256) {
    int c = g >> 6, t = g & 63;
    hl[c * 68 + t] = (t0 + t < TOUT) ? hmain[((size_t)b * 128 + c) * TOUT + t0 + t] : 0.f;
  }
  if (tid < 128) ql[tid] = q[b * 128 + tid];
  __syncthreads();
  {
    int t = tid & 63, cy = tid >> 6;
    float s = 0.f;
#pragma unroll
    for (int cc = 0; cc < 32; ++cc) s = fmaf(hl[(cy * 32 + cc) * 68 + t], ql[cy * 32 + cc], s);
    red[cy * 64 + t] = s;
  }
  __syncthreads();
  if (tid < 64) {
    float s = red[tid] + red[64 + tid] + red[128 + tid] + red[192 + tid];
    gl[tid] = sigmoidf_(s);
  }
  __syncthreads();
  {
    int c = tid >> 1, th = tid & 1;
    float m = -INFINITY;
#pragma unroll
    for (int tt = 0; tt < 32; ++tt) {
      int t = th * 32 + tt;
      if (t0 + t < TOUT) m = fmaxf(m, hl[c * 68 + t] * gl[t]);
    }
    red[c * 2 + th] = m;
  }
  __syncthreads();
  if (tid < 128) out_part[((size_t)b * 128 + tid) * NT2 + tile] = fmaxf(red[tid * 2], red[tid * 2 + 1]);
}

// ---------------------------------------------------------------------------
// Kernel 5: final max over tiles -> d_out (B,C) row-major.
__global__ void final_max(const float* __restrict__ out_part, float* __restrict__ out) {
  int idx = blockIdx.x * 256 + threadIdx.x;
  if (idx < 512) {
    float m = -INFINITY;
    for (int tl = 0; tl < NT2; ++tl) m = fmaxf(m, out_part[(size_t)idx * NT2 + tl]);
    out[idx] = m;
  }
}

// ---------------------------------------------------------------------------
extern "C" void kernel_launch(void* const* d_in, const int* in_sizes, int n_in,
                              void* d_out, int out_size, void* d_ws, size_t ws_size,
                              hipStream_t stream) {
  const float* x      = (const float*)d_in[0];
  const float* ctx_w  = (const float*)d_in[1];
  const float* ctx_b  = (const float*)d_in[2];
  const float* ctx_sw = (const float*)d_in[3];
  const float* ctx_sb = (const float*)d_in[4];
  const float* main_w = (const float*)d_in[5];
  const float* main_b = (const float*)d_in[6];
  const float* main_sw= (const float*)d_in[7];
  const float* main_sb= (const float*)d_in[8];
  const float* gp_w   = (const float*)d_in[9];
  const float* gp_b   = (const float*)d_in[10];

  char* w = (char*)d_ws;
  __hip_bfloat16* xb2 = (__hip_bfloat16*)(w);              // 4*2^23*2   = 67,108,864
  __hip_bfloat16* Wn2 = (__hip_bfloat16*)(w + 67108864);   // 512*4096*2 =  4,194,304
  float* bias_t  = (float*)(w + 71303168);                 // 512*4
  float* u2      = (float*)(w + 71305216);                 // 512*4*TP*4 = 16,023,552
  float* hmain   = (float*)(w + 87328768);                 // 4*128*1953*4 = 3,999,744
  float* gct_part= (float*)(w + 91328512);                 // 4*128*31*4 = 63,488
  float* q       = (float*)(w + 91392000);                 // 512*4
  float* out_part= (float*)(w + 91394048);                 // 63,488

  prep_inputs<<<NCH + 16384, 256, 0, stream>>>(x, ctx_w, ctx_b, main_w, main_b,
                                               xb2, Wn2, bias_t);
  mfma_gemm<<<256, 512, 0, stream>>>(xb2, Wn2, u2);
  share_act<<<dim3(NT2, B_, 2), 256, 0, stream>>>(u2, bias_t, ctx_sw, ctx_sb,
                                                  main_sw, main_sb, hmain, gct_part);
  gct_q<<<B_, 128, 0, stream>>>(gct_part, gp_w, gp_b, q);
  gate_max<<<dim3(NT2, B_), 256, 0, stream>>>(hmain, q, out_part);
  final_max<<<2, 256, 0, stream>>>(out_part, (float*)d_out);
}